// Round 5
// baseline (656.294 us; speedup 1.0000x reference)
//
#include <hip/hip_runtime.h>

#define B_SZ  1024
#define NSEQ  512
#define D_INP 30
#define H     64
#define MB    16      // batch rows per block
#define TCH   8       // x timesteps staged per chunk
#define L2E   1.4426950408889634f

typedef short s16x8 __attribute__((ext_vector_type(8)));
typedef float f32x4 __attribute__((ext_vector_type(4)));

#if __has_builtin(__builtin_amdgcn_exp2f)
#define EXP2(x) __builtin_amdgcn_exp2f(x)
#else
#define EXP2(x) exp2f(x)
#endif

__device__ __forceinline__ float rcp_f(float v) { return __builtin_amdgcn_rcpf(v); }

__device__ __forceinline__ f32x4 mfma16(s16x8 a, s16x8 b, f32x4 c) {
  return __builtin_amdgcn_mfma_f32_16x16x32_bf16(a, b, c, 0, 0, 0);
}

// split 8 fp32 -> bf16 hi (truncate) + bf16 lo (residual, truncate)
__device__ __forceinline__ void split8(const float* f, s16x8& hi, s16x8& lo) {
#pragma unroll
  for (int i = 0; i < 8; ++i) {
    unsigned ub = __float_as_uint(f[i]);
    hi[i] = (short)(ub >> 16);
    float hf = __uint_as_float(ub & 0xFFFF0000u);
    float lf = f[i] - hf;
    lo[i] = (short)(__float_as_uint(lf) >> 16);
  }
}

// ---------------------------------------------------------------------------
// Kernel A: fold FC into the input-side gate GEMM (fp32).
// ---------------------------------------------------------------------------
__global__ __launch_bounds__(256) void prep_kernel(
    const float* __restrict__ W_fc, const float* __restrict__ b_fc,
    const float* __restrict__ W_ih, const float* __restrict__ b_ih,
    const float* __restrict__ b_hh,
    float* __restrict__ wsW, float* __restrict__ wsB) {
  __shared__ float fc[H * D_INP];
  __shared__ float bfc[H];
  const int u = threadIdx.x;
  for (int i = u; i < H * D_INP; i += 256) fc[i] = W_fc[i];
  if (u < H) bfc[u] = b_fc[u];
  __syncthreads();

  float wih[H];
#pragma unroll
  for (int i = 0; i < H; ++i) wih[i] = W_ih[u * H + i];

  for (int k = 0; k < D_INP; ++k) {
    float s = 0.f;
#pragma unroll
    for (int i = 0; i < H; ++i) s = fmaf(wih[i], fc[i * D_INP + k], s);
    wsW[u * 32 + k] = s;
  }
  wsW[u * 32 + 30] = 0.f;
  wsW[u * 32 + 31] = 0.f;

  float bb = b_ih[u] + b_hh[u];
#pragma unroll
  for (int i = 0; i < H; ++i) bb = fmaf(wih[i], bfc[i], bb);
  wsB[u] = bb;
}

// ---------------------------------------------------------------------------
// Kernel B: MFMA LSTM. 64 blocks x 256 threads; block owns 16 batch rows.
// Wave w owns N-tiles {w, w+4, w+8, w+12}: all 4 gates of hidden elem
// j = 16w+low co-located per lane. h exchanged via two bf16 LDS planes
// (hi/lo), row stride 72 shorts (16B aligned, conflict-balanced).
// Weights prescaled by log2e (2*log2e for g-gate) -> raw exp2 activations.
// Logits per step via shuffle-reduce + LDS atomic (symmetric waves).
// ---------------------------------------------------------------------------
__global__ __launch_bounds__(256, 1) void lstm_mfma(
    const float* __restrict__ x, const float* __restrict__ W_hh,
    const float* __restrict__ wsW, const float* __restrict__ wsB,
    const float* __restrict__ W_last, float* __restrict__ out) {

  __shared__ short xa[2][TCH][2][64][8];       // x A-frags bf16 hi/lo, 32 KB
  __shared__ short hpl[2][2][MB][72];          // h planes [buf][hi/lo][row][k], 9.2 KB
  __shared__ float logitsT[NSEQ][MB];          // accumulated logits, 32 KB

  const int u   = threadIdx.x;
  const int w   = u >> 6;       // wave id
  const int l   = u & 63;       // lane
  const int low = l & 15;
  const int q   = l >> 4;
  const int b0  = blockIdx.x * MB;

  // ---- B-fragments (weights), prescaled, hi/lo split, in registers ----
  s16x8 whh_h[4][2], whh_l[4][2], wcb_h[4], wcb_l[4];
  float biasv[4];
#pragma unroll
  for (int g = 0; g < 4; ++g) {
    const float sc = (g == 2) ? (2.0f * L2E) : L2E;
    const int n = 64 * g + 16 * w + low;
#pragma unroll
    for (int kt = 0; kt < 2; ++kt) {
      float tmp[8];
      const float* p = W_hh + n * H + kt * 32 + q * 8;
#pragma unroll
      for (int j = 0; j < 8; ++j) tmp[j] = p[j] * sc;
      split8(tmp, whh_h[g][kt], whh_l[g][kt]);
    }
    {
      float tmp[8];
      const float* p = wsW + n * 32 + q * 8;
#pragma unroll
      for (int j = 0; j < 8; ++j) tmp[j] = p[j] * sc;
      split8(tmp, wcb_h[g], wcb_l[g]);
    }
    biasv[g] = wsB[n] * sc;
  }
  const float wlv = W_last[16 * w + low];   // logit weight for this lane's col

  // zero h planes and logit accumulator
  for (int i = u; i < 2 * 2 * MB * 72 / 2; i += 256) ((int*)hpl)[i] = 0;
  for (int i = u; i < NSEQ * MB; i += 256) ((float*)logitsT)[i] = 0.f;

  // ---- x staging: thread covers (row=low, k=q*8+2w, +1) ----
  const int sk = q * 8 + (w << 1);
  const bool svalid = (sk < D_INP);
  const float* xbase = x + (size_t)(b0 + low) * NSEQ * D_INP + sk;

  float2 pf[TCH];
  auto stage_load = [&](int t0) {
#pragma unroll
    for (int s = 0; s < TCH; ++s)
      pf[s] = svalid ? *(const float2*)(xbase + (size_t)(t0 + s) * D_INP)
                     : make_float2(0.f, 0.f);
  };
  auto stage_write = [&](int buf) {
#pragma unroll
    for (int s = 0; s < TCH; ++s) {
      unsigned u0 = __float_as_uint(pf[s].x);
      unsigned u1 = __float_as_uint(pf[s].y);
      unsigned hw = (u1 & 0xFFFF0000u) | (u0 >> 16);
      float l0 = pf[s].x - __uint_as_float(u0 & 0xFFFF0000u);
      float l1 = pf[s].y - __uint_as_float(u1 & 0xFFFF0000u);
      unsigned lw = (__float_as_uint(l1) & 0xFFFF0000u) | (__float_as_uint(l0) >> 16);
      *(unsigned*)&xa[buf][s][0][l][w << 1] = hw;
      *(unsigned*)&xa[buf][s][1][l][w << 1] = lw;
    }
  };

  stage_load(0);
  stage_write(0);
  __syncthreads();

  f32x4 c4 = {0.f, 0.f, 0.f, 0.f};

#pragma unroll 1
  for (int t = 0; t < NSEQ; ++t) {
    const int tt = t & (TCH - 1);
    const int cb = (t >> 3) & 1;
    if (tt == 0 && t + TCH < NSEQ) stage_load(t + TCH);

    // x A-frags (pre-split bf16, staged)
    s16x8 xah = *(const s16x8*)&xa[cb][tt][0][l][0];
    s16x8 xal = *(const s16x8*)&xa[cb][tt][1][l][0];

    // h A-frags: direct b128 reads from bf16 planes (no unpack)
    const short* hp0 = &hpl[(t + 1) & 1][0][low][0];
    const short* hp1 = &hpl[(t + 1) & 1][1][low][0];
    s16x8 ah[2], al[2];
#pragma unroll
    for (int kt = 0; kt < 2; ++kt) {
      ah[kt] = *(const s16x8*)(hp0 + kt * 32 + q * 8);
      al[kt] = *(const s16x8*)(hp1 + kt * 32 + q * 8);
    }

    // 12 independent MFMA chains (depth <= 3), add at end
    f32x4 acc[4];
#pragma unroll
    for (int g = 0; g < 4; ++g) {
      f32x4 a = {biasv[g], biasv[g], biasv[g], biasv[g]};
      a = mfma16(xah, wcb_h[g], a);
      a = mfma16(ah[0], whh_h[g][0], a);
      a = mfma16(ah[1], whh_h[g][1], a);
      f32x4 b = {0.f, 0.f, 0.f, 0.f};
      b = mfma16(xah, wcb_l[g], b);
      b = mfma16(ah[0], whh_l[g][0], b);
      b = mfma16(ah[1], whh_l[g][1], b);
      f32x4 c = {0.f, 0.f, 0.f, 0.f};
      c = mfma16(xal, wcb_h[g], c);
      c = mfma16(al[0], whh_h[g][0], c);
      c = mfma16(al[1], whh_h[g][1], c);
      acc[g] = (a + b) + c;
    }

    // per-lane LSTM cell update (4 cells: rows q*4+r, col 16w+low)
    short* d_hi = &hpl[t & 1][0][0][0];
    short* d_lo = &hpl[t & 1][1][0][0];
    float pr[4];
#pragma unroll
    for (int r = 0; r < 4; ++r) {
      float gi = rcp_f(1.0f + EXP2(-acc[0][r]));
      float gf = rcp_f(1.0f + EXP2(-acc[1][r]));
      float gg = 1.0f - 2.0f * rcp_f(1.0f + EXP2(acc[2][r]));
      float go = rcp_f(1.0f + EXP2(-acc[3][r]));
      float cc = fmaf(gf, c4[r], gi * gg);
      c4[r] = cc;
      float h = go * (1.0f - 2.0f * rcp_f(1.0f + EXP2(cc * (2.0f * L2E))));
      unsigned uh = __float_as_uint(h);
      float lf = h - __uint_as_float(uh & 0xFFFF0000u);
      const int idx = (q * 4 + r) * 72 + 16 * w + low;
      d_hi[idx] = (short)(uh >> 16);
      d_lo[idx] = (short)(__float_as_uint(lf) >> 16);
      pr[r] = h * wlv;
    }

    // logit: reduce this wave's 16-col partials, atomically add across waves
#pragma unroll
    for (int r = 0; r < 4; ++r) {
#pragma unroll
      for (int m = 1; m < 16; m <<= 1) pr[r] += __shfl_xor(pr[r], m, 64);
    }
    if (low == 0) {
#pragma unroll
      for (int r = 0; r < 4; ++r) atomicAdd(&logitsT[t][q * 4 + r], pr[r]);
    }

    if (tt == TCH / 2 && t + TCH / 2 < NSEQ) stage_write(cb ^ 1);
    __syncthreads();
  }

  // ---- softmax over time: row m = u>>4, lanes cover t = (u&15) + 16s ----
  {
    const int m = u >> 4, li = u & 15;
    float lv[32];
    float mx = -3.0e38f;
#pragma unroll
    for (int s = 0; s < 32; ++s) {
      lv[s] = logitsT[li + 16 * s][m];
      mx = fmaxf(mx, lv[s]);
    }
#pragma unroll
    for (int d = 1; d < 16; d <<= 1) mx = fmaxf(mx, __shfl_xor(mx, d, 16));
    float sum = 0.f;
#pragma unroll
    for (int s = 0; s < 32; ++s) { lv[s] = __expf(lv[s] - mx); sum += lv[s]; }
#pragma unroll
    for (int d = 1; d < 16; d <<= 1) sum += __shfl_xor(sum, d, 16);
    float inv = 1.0f / sum;
#pragma unroll
    for (int s = 0; s < 32; ++s)
      out[(size_t)(b0 + m) * NSEQ + li + 16 * s] = lv[s] * inv;
  }
}

// ---------------------------------------------------------------------------
extern "C" void kernel_launch(void* const* d_in, const int* in_sizes, int n_in,
                              void* d_out, int out_size, void* d_ws, size_t ws_size,
                              hipStream_t stream) {
  const float* x      = (const float*)d_in[0];
  const float* W_fc   = (const float*)d_in[1];
  const float* b_fc   = (const float*)d_in[2];
  const float* W_ih   = (const float*)d_in[3];
  const float* W_hh   = (const float*)d_in[4];
  const float* b_ih   = (const float*)d_in[5];
  const float* b_hh   = (const float*)d_in[6];
  const float* W_last = (const float*)d_in[7];
  // d_in[8] = b_last: cancels in softmax.

  float* out = (float*)d_out;
  float* wsW = (float*)d_ws;          // 256*32 floats
  float* wsB = wsW + 256 * 32;        // 256 floats

  prep_kernel<<<1, 256, 0, stream>>>(W_fc, b_fc, W_ih, b_ih, b_hh, wsW, wsB);
  lstm_mfma<<<B_SZ / MB, 256, 0, stream>>>(x, W_hh, wsW, wsB, W_last, out);
}

// Round 6
// 518.436 us; speedup vs baseline: 1.2659x; 1.2659x over previous
//
#include <hip/hip_runtime.h>

#define B_SZ  1024
#define NSEQ  512
#define D_INP 30
#define H     64
#define MB    16
#define TCH   8
#define L2E   1.4426950408889634f

typedef short s16x8 __attribute__((ext_vector_type(8)));
typedef float f32x4 __attribute__((ext_vector_type(4)));

#if __has_builtin(__builtin_amdgcn_exp2f)
#define EXP2(x) __builtin_amdgcn_exp2f(x)
#else
#define EXP2(x) exp2f(x)
#endif

__device__ __forceinline__ float rcp_f(float v) { return __builtin_amdgcn_rcpf(v); }

__device__ __forceinline__ f32x4 mfma16(s16x8 a, s16x8 b, f32x4 c) {
  return __builtin_amdgcn_mfma_f32_16x16x32_bf16(a, b, c, 0, 0, 0);
}

// split 8 fp32 -> bf16 hi (truncate) + bf16 lo (residual); pair is exact to ~2^-17
__device__ __forceinline__ void split8(const float* f, s16x8& hi, s16x8& lo) {
#pragma unroll
  for (int i = 0; i < 8; ++i) {
    unsigned ub = __float_as_uint(f[i]);
    hi[i] = (short)(ub >> 16);
    float hf = __uint_as_float(ub & 0xFFFF0000u);
    float lf = f[i] - hf;
    lo[i] = (short)(__float_as_uint(lf) >> 16);
  }
}

// fp32 -> bf16 round-to-nearest-even (err <= 2^-9 relative)
__device__ __forceinline__ short bf16_rne(float f) {
  unsigned u = __float_as_uint(f);
  unsigned r = (u + 0x7FFFu + ((u >> 16) & 1u)) >> 16;
  return (short)r;
}

// ---------------------------------------------------------------------------
// Kernel A: fold FC into the input-side gate GEMM (fp32).
// ---------------------------------------------------------------------------
__global__ __launch_bounds__(256) void prep_kernel(
    const float* __restrict__ W_fc, const float* __restrict__ b_fc,
    const float* __restrict__ W_ih, const float* __restrict__ b_ih,
    const float* __restrict__ b_hh,
    float* __restrict__ wsW, float* __restrict__ wsB) {
  __shared__ float fc[H * D_INP];
  __shared__ float bfc[H];
  const int u = threadIdx.x;
  for (int i = u; i < H * D_INP; i += 256) fc[i] = W_fc[i];
  if (u < H) bfc[u] = b_fc[u];
  __syncthreads();

  float wih[H];
#pragma unroll
  for (int i = 0; i < H; ++i) wih[i] = W_ih[u * H + i];

  for (int k = 0; k < D_INP; ++k) {
    float s = 0.f;
#pragma unroll
    for (int i = 0; i < H; ++i) s = fmaf(wih[i], fc[i * D_INP + k], s);
    wsW[u * 32 + k] = s;
  }
  wsW[u * 32 + 30] = 0.f;
  wsW[u * 32 + 31] = 0.f;

  float bb = b_ih[u] + b_hh[u];
#pragma unroll
  for (int i = 0; i < H; ++i) bb = fmaf(wih[i], bfc[i], bb);
  wsB[u] = bb;
}

// ---------------------------------------------------------------------------
// Kernel B: MFMA LSTM. 64 blocks x 256 threads; block owns 16 batch rows.
// Wave w owns N-tiles {w, w+4, w+8, w+12}: all 4 gates of hidden elem
// j = 16w+low co-located per lane. h: single RNE-bf16 LDS plane (2-term
// numerics: h_hi * (w_hi + w_lo)); x: hi+lo planes (3-term, exact).
// Weights prescaled by log2e (2*log2e for g-gate) -> raw exp2 activations.
// Logits: rotating extra MFMA N-tile (wave t&3), one step delayed.
// ---------------------------------------------------------------------------
__global__ __launch_bounds__(256, 1) void lstm_mfma(
    const float* __restrict__ x, const float* __restrict__ W_hh,
    const float* __restrict__ wsW, const float* __restrict__ wsB,
    const float* __restrict__ W_last, float* __restrict__ out) {

  __shared__ short xa[2][TCH][2][64][8];   // x A-frags bf16 hi/lo, 32 KB
  __shared__ short hpl[2][MB][72];         // h bf16 plane, dbuf, 4.6 KB
  __shared__ float logitsT[NSEQ + 1][MB];  // logit of h_{t-1} at slot t, 32.8 KB

  const int u   = threadIdx.x;
  const int w   = u >> 6;
  const int l   = u & 63;
  const int low = l & 15;
  const int q   = l >> 4;
  const int b0  = blockIdx.x * MB;

  // ---- B-fragments (weights), prescaled, hi/lo split, in registers ----
  s16x8 whh_h[4][2], whh_l[4][2], wcb_h[4], wcb_l[4], wl_h[2], wl_l[2];
  float biasv[4];
#pragma unroll
  for (int g = 0; g < 4; ++g) {
    const float sc = (g == 2) ? (2.0f * L2E) : L2E;
    const int n = 64 * g + 16 * w + low;
#pragma unroll
    for (int kt = 0; kt < 2; ++kt) {
      float tmp[8];
      const float* p = W_hh + n * H + kt * 32 + q * 8;
#pragma unroll
      for (int j = 0; j < 8; ++j) tmp[j] = p[j] * sc;
      split8(tmp, whh_h[g][kt], whh_l[g][kt]);
    }
    {
      float tmp[8];
      const float* p = wsW + n * 32 + q * 8;
#pragma unroll
      for (int j = 0; j < 8; ++j) tmp[j] = p[j] * sc;
      split8(tmp, wcb_h[g], wcb_l[g]);
    }
    biasv[g] = wsB[n] * sc;
  }
#pragma unroll
  for (int kt = 0; kt < 2; ++kt) {
    float tmp[8];
#pragma unroll
    for (int j = 0; j < 8; ++j)
      tmp[j] = (low == 0) ? W_last[kt * 32 + q * 8 + j] : 0.0f;
    split8(tmp, wl_h[kt], wl_l[kt]);
  }

  // zero h planes (2*16*72 shorts = 1152 ints)
  for (int i = u; i < 2 * MB * 72 / 2; i += 256) ((int*)hpl)[i] = 0;

  // ---- x staging: thread u builds dest-lane l's full 16B A-frag row ----
  // dest lane l -> (row = l&15, k-block q = l>>4); wave w covers s = 2w+c.
  const float* xrow = x + (size_t)(b0 + low) * NSEQ * D_INP + q * 8;
  float xv[2][8];
  auto stage_load = [&](int t0) {
#pragma unroll
    for (int c = 0; c < 2; ++c) {
      const float* p = xrow + (size_t)(t0 + 2 * w + c) * D_INP;
      float2 v0 = *(const float2*)(p);       // k=q8+0,1   (8B aligned: even off)
      float2 v1 = *(const float2*)(p + 2);   // k=q8+2,3
      float2 v2 = *(const float2*)(p + 4);   // k=q8+4,5
      float2 v3 = (q < 3) ? *(const float2*)(p + 6) : make_float2(0.f, 0.f);
      xv[c][0] = v0.x; xv[c][1] = v0.y; xv[c][2] = v1.x; xv[c][3] = v1.y;
      xv[c][4] = v2.x; xv[c][5] = v2.y; xv[c][6] = v3.x; xv[c][7] = v3.y;
    }
  };
  auto stage_write = [&](int buf) {
#pragma unroll
    for (int c = 0; c < 2; ++c) {
      s16x8 hi, lo;
      split8(xv[c], hi, lo);
      const int s = 2 * w + c;
      *(s16x8*)&xa[buf][s][0][l][0] = hi;   // b128, 16B lane stride: conflict-free
      *(s16x8*)&xa[buf][s][1][l][0] = lo;
    }
  };

  stage_load(0);
  stage_write(0);
  __syncthreads();

  f32x4 c4 = {0.f, 0.f, 0.f, 0.f};

  for (int t = 0; t < NSEQ; ++t) {
    const int tt = t & (TCH - 1);
    const int cb = (t >> 3) & 1;
    if (tt == 0 && t + TCH < NSEQ) stage_load(t + TCH);

    // x A-frags (pre-split bf16, staged)
    s16x8 xah = *(const s16x8*)&xa[cb][tt][0][l][0];
    s16x8 xal = *(const s16x8*)&xa[cb][tt][1][l][0];

    // h A-frag: single bf16 plane, 2 ds_read_b128
    const short* hp = &hpl[(t + 1) & 1][low][0];
    s16x8 ah0 = *(const s16x8*)(hp + q * 8);
    s16x8 ah1 = *(const s16x8*)(hp + 32 + q * 8);

    // 8 chains (depth <=4), 7 MFMAs per gate
    f32x4 acc[4];
#pragma unroll
    for (int g = 0; g < 4; ++g) {
      f32x4 a = {biasv[g], biasv[g], biasv[g], biasv[g]};
      a = mfma16(xah, wcb_h[g], a);
      a = mfma16(ah0, whh_h[g][0], a);
      a = mfma16(ah1, whh_h[g][1], a);
      f32x4 b = {0.f, 0.f, 0.f, 0.f};
      b = mfma16(xah, wcb_l[g], b);
      b = mfma16(xal, wcb_h[g], b);
      b = mfma16(ah0, whh_l[g][0], b);
      b = mfma16(ah1, whh_l[g][1], b);
      acc[g] = a + b;
    }

    // logit_{t-1}: rotating extra N-tile (4 MFMAs, 2 chains of 2)
    if (w == (t & 3)) {
      f32x4 aL = {0.f, 0.f, 0.f, 0.f};
      aL = mfma16(ah0, wl_h[0], aL);
      aL = mfma16(ah1, wl_h[1], aL);
      f32x4 bL = {0.f, 0.f, 0.f, 0.f};
      bL = mfma16(ah0, wl_l[0], bL);
      bL = mfma16(ah1, wl_l[1], bL);
      aL = aL + bL;
      if (low == 0) *(f32x4*)&logitsT[t][q * 4] = aL;
    }

    // per-lane LSTM cell update (rows q*4+r, col 16w+low)
    short* hw = &hpl[t & 1][0][0];
#pragma unroll
    for (int r = 0; r < 4; ++r) {
      float gi = rcp_f(1.0f + EXP2(-acc[0][r]));
      float gf = rcp_f(1.0f + EXP2(-acc[1][r]));
      float gg = 1.0f - 2.0f * rcp_f(1.0f + EXP2(acc[2][r]));
      float go = rcp_f(1.0f + EXP2(-acc[3][r]));
      float cc = fmaf(gf, c4[r], gi * gg);
      c4[r] = cc;
      float h = go * (1.0f - 2.0f * rcp_f(1.0f + EXP2(cc * (2.0f * L2E))));
      hw[(q * 4 + r) * 72 + 16 * w + low] = bf16_rne(h);
    }

    if (tt == 4 && t + 4 < NSEQ) stage_write(cb ^ 1);
    __syncthreads();
  }

  // final logit from h_511 (in hpl[1])
  if (w == 0) {
    const short* hp = &hpl[1][low][0];
    s16x8 ah0 = *(const s16x8*)(hp + q * 8);
    s16x8 ah1 = *(const s16x8*)(hp + 32 + q * 8);
    f32x4 aL = {0.f, 0.f, 0.f, 0.f};
    aL = mfma16(ah0, wl_h[0], aL);
    aL = mfma16(ah1, wl_h[1], aL);
    f32x4 bL = {0.f, 0.f, 0.f, 0.f};
    bL = mfma16(ah0, wl_l[0], bL);
    bL = mfma16(ah1, wl_l[1], bL);
    aL = aL + bL;
    if (low == 0) *(f32x4*)&logitsT[NSEQ][q * 4] = aL;
  }
  __syncthreads();

  // ---- softmax over time: row m = u>>4, lanes cover t = (u&15) + 16s ----
  {
    const int m = u >> 4, li = u & 15;
    float lv[32];
    float mx = -3.0e38f;
#pragma unroll
    for (int s = 0; s < 32; ++s) {
      lv[s] = logitsT[1 + li + 16 * s][m];
      mx = fmaxf(mx, lv[s]);
    }
#pragma unroll
    for (int d = 1; d < 16; d <<= 1) mx = fmaxf(mx, __shfl_xor(mx, d, 16));
    float sum = 0.f;
#pragma unroll
    for (int s = 0; s < 32; ++s) { lv[s] = __expf(lv[s] - mx); sum += lv[s]; }
#pragma unroll
    for (int d = 1; d < 16; d <<= 1) sum += __shfl_xor(sum, d, 16);
    float inv = 1.0f / sum;
#pragma unroll
    for (int s = 0; s < 32; ++s)
      out[(size_t)(b0 + m) * NSEQ + li + 16 * s] = lv[s] * inv;
  }
}

// ---------------------------------------------------------------------------
extern "C" void kernel_launch(void* const* d_in, const int* in_sizes, int n_in,
                              void* d_out, int out_size, void* d_ws, size_t ws_size,
                              hipStream_t stream) {
  const float* x      = (const float*)d_in[0];
  const float* W_fc   = (const float*)d_in[1];
  const float* b_fc   = (const float*)d_in[2];
  const float* W_ih   = (const float*)d_in[3];
  const float* W_hh   = (const float*)d_in[4];
  const float* b_ih   = (const float*)d_in[5];
  const float* b_hh   = (const float*)d_in[6];
  const float* W_last = (const float*)d_in[7];
  // d_in[8] = b_last: cancels in softmax.

  float* out = (float*)d_out;
  float* wsW = (float*)d_ws;          // 256*32 floats
  float* wsB = wsW + 256 * 32;        // 256 floats

  prep_kernel<<<1, 256, 0, stream>>>(W_fc, b_fc, W_ih, b_ih, b_hh, wsW, wsB);
  lstm_mfma<<<B_SZ / MB, 256, 0, stream>>>(x, W_hh, wsW, wsB, W_last, out);
}

// Round 7
// 439.408 us; speedup vs baseline: 1.4936x; 1.1798x over previous
//
#include <hip/hip_runtime.h>

#define B_SZ  1024
#define NSEQ  512
#define D_INP 30
#define H     64
#define MB    16
#define TCH   8
#define L2E   1.4426950408889634f

typedef short s16x8 __attribute__((ext_vector_type(8)));
typedef float f32x4 __attribute__((ext_vector_type(4)));

#if __has_builtin(__builtin_amdgcn_exp2f)
#define EXP2(x) __builtin_amdgcn_exp2f(x)
#else
#define EXP2(x) exp2f(x)
#endif

__device__ __forceinline__ float rcp_f(float v) { return __builtin_amdgcn_rcpf(v); }

__device__ __forceinline__ f32x4 mfma16(s16x8 a, s16x8 b, f32x4 c) {
  return __builtin_amdgcn_mfma_f32_16x16x32_bf16(a, b, c, 0, 0, 0);
}

// fp32 -> bf16 round-to-nearest-even
__device__ __forceinline__ short bf16_rne(float f) {
  unsigned u = __float_as_uint(f);
  unsigned r = (u + 0x7FFFu + ((u >> 16) & 1u)) >> 16;
  return (short)r;
}

// 8 fp32 -> single RNE bf16 plane
__device__ __forceinline__ s16x8 rne8(const float* f) {
  s16x8 o;
#pragma unroll
  for (int i = 0; i < 8; ++i) o[i] = bf16_rne(f[i]);
  return o;
}

// split 8 fp32 -> bf16 hi (truncate) + bf16 lo (residual) — 2-term exact path
__device__ __forceinline__ void split8(const float* f, s16x8& hi, s16x8& lo) {
#pragma unroll
  for (int i = 0; i < 8; ++i) {
    unsigned ub = __float_as_uint(f[i]);
    hi[i] = (short)(ub >> 16);
    float hf = __uint_as_float(ub & 0xFFFF0000u);
    float lf = f[i] - hf;
    lo[i] = (short)(__float_as_uint(lf) >> 16);
  }
}

// ---------------------------------------------------------------------------
// Kernel A: fold FC into the input-side gate GEMM (fp32).
// ---------------------------------------------------------------------------
__global__ __launch_bounds__(256) void prep_kernel(
    const float* __restrict__ W_fc, const float* __restrict__ b_fc,
    const float* __restrict__ W_ih, const float* __restrict__ b_ih,
    const float* __restrict__ b_hh,
    float* __restrict__ wsW, float* __restrict__ wsB) {
  __shared__ float fc[H * D_INP];
  __shared__ float bfc[H];
  const int u = threadIdx.x;
  for (int i = u; i < H * D_INP; i += 256) fc[i] = W_fc[i];
  if (u < H) bfc[u] = b_fc[u];
  __syncthreads();

  float wih[H];
#pragma unroll
  for (int i = 0; i < H; ++i) wih[i] = W_ih[u * H + i];

  for (int k = 0; k < D_INP; ++k) {
    float s = 0.f;
#pragma unroll
    for (int i = 0; i < H; ++i) s = fmaf(wih[i], fc[i * D_INP + k], s);
    wsW[u * 32 + k] = s;
  }
  wsW[u * 32 + 30] = 0.f;
  wsW[u * 32 + 31] = 0.f;

  float bb = b_ih[u] + b_hh[u];
#pragma unroll
  for (int i = 0; i < H; ++i) bb = fmaf(wih[i], bfc[i], bb);
  wsB[u] = bb;
}

// ---------------------------------------------------------------------------
// Kernel B: MFMA LSTM. 64 blocks x 256 threads; block owns 16 batch rows.
// Wave w owns N-tiles {w, w+4, w+8, w+12}: all 4 gates of hidden elem
// j = 16w+low co-located per lane. SINGLE-PLANE RNE bf16 gate path:
// 12 MFMAs/step (3 per gate, depth-3 chains). Logit weight stays 2-term
// (output path is undamped). Weights prescaled by log2e (2*log2e g-gate).
// ---------------------------------------------------------------------------
__global__ __launch_bounds__(256, 1) void lstm_mfma(
    const float* __restrict__ x, const float* __restrict__ W_hh,
    const float* __restrict__ wsW, const float* __restrict__ wsB,
    const float* __restrict__ W_last, float* __restrict__ out) {

  __shared__ short xa[2][TCH][64][8];      // x A-frags RNE bf16, 16 KB
  __shared__ short hpl[2][MB][72];         // h bf16 plane, dbuf, 4.6 KB
  __shared__ float logitsT[NSEQ + 1][MB];  // logit of h_{t-1} at slot t, 32.8 KB

  const int u   = threadIdx.x;
  const int w   = u >> 6;
  const int l   = u & 63;
  const int low = l & 15;
  const int q   = l >> 4;
  const int b0  = blockIdx.x * MB;

  // ---- B-fragments: single-plane RNE (gates), 2-term (logit) ----
  s16x8 whh[4][2], wcb[4], wl_h[2], wl_l[2];
  float biasv[4];
#pragma unroll
  for (int g = 0; g < 4; ++g) {
    const float sc = (g == 2) ? (2.0f * L2E) : L2E;
    const int n = 64 * g + 16 * w + low;
#pragma unroll
    for (int kt = 0; kt < 2; ++kt) {
      float tmp[8];
      const float* p = W_hh + n * H + kt * 32 + q * 8;
#pragma unroll
      for (int j = 0; j < 8; ++j) tmp[j] = p[j] * sc;
      whh[g][kt] = rne8(tmp);
    }
    {
      float tmp[8];
      const float* p = wsW + n * 32 + q * 8;
#pragma unroll
      for (int j = 0; j < 8; ++j) tmp[j] = p[j] * sc;
      wcb[g] = rne8(tmp);
    }
    biasv[g] = wsB[n] * sc;
  }
#pragma unroll
  for (int kt = 0; kt < 2; ++kt) {
    float tmp[8];
#pragma unroll
    for (int j = 0; j < 8; ++j)
      tmp[j] = (low == 0) ? W_last[kt * 32 + q * 8 + j] : 0.0f;
    split8(tmp, wl_h[kt], wl_l[kt]);
  }

  // zero h planes
  for (int i = u; i < 2 * MB * 72 / 2; i += 256) ((int*)hpl)[i] = 0;

  // ---- x staging: thread u builds dest-lane l's 16B A-frag row ----
  const float* xrow = x + (size_t)(b0 + low) * NSEQ * D_INP + q * 8;
  float xv[2][8];
  auto stage_load = [&](int t0) {
#pragma unroll
    for (int c = 0; c < 2; ++c) {
      const float* p = xrow + (size_t)(t0 + 2 * w + c) * D_INP;
      float2 v0 = *(const float2*)(p);
      float2 v1 = *(const float2*)(p + 2);
      float2 v2 = *(const float2*)(p + 4);
      float2 v3 = (q < 3) ? *(const float2*)(p + 6) : make_float2(0.f, 0.f);
      xv[c][0] = v0.x; xv[c][1] = v0.y; xv[c][2] = v1.x; xv[c][3] = v1.y;
      xv[c][4] = v2.x; xv[c][5] = v2.y; xv[c][6] = v3.x; xv[c][7] = v3.y;
    }
  };
  auto stage_write = [&](int buf) {
#pragma unroll
    for (int c = 0; c < 2; ++c) {
      const int s = 2 * w + c;
      *(s16x8*)&xa[buf][s][l][0] = rne8(xv[c]);  // b128, conflict-free
    }
  };

  stage_load(0);
  stage_write(0);
  __syncthreads();

  f32x4 c4 = {0.f, 0.f, 0.f, 0.f};

  for (int t = 0; t < NSEQ; ++t) {
    const int tt = t & (TCH - 1);
    const int cb = (t >> 3) & 1;
    if (tt == 0 && t + TCH < NSEQ) stage_load(t + TCH);

    // x A-frag (pre-split RNE bf16)
    s16x8 xah = *(const s16x8*)&xa[cb][tt][l][0];

    // h A-frag: single bf16 plane, 2 ds_read_b128
    const short* hp = &hpl[(t + 1) & 1][low][0];
    s16x8 ah0 = *(const s16x8*)(hp + q * 8);
    s16x8 ah1 = *(const s16x8*)(hp + 32 + q * 8);

    // 4 chains of depth 3: 12 MFMAs
    f32x4 acc[4];
#pragma unroll
    for (int g = 0; g < 4; ++g) {
      f32x4 a = {biasv[g], biasv[g], biasv[g], biasv[g]};
      a = mfma16(xah, wcb[g], a);
      a = mfma16(ah0, whh[g][0], a);
      a = mfma16(ah1, whh[g][1], a);
      acc[g] = a;
    }

    // logit_{t-1}: rotating extra N-tile (4 MFMAs, 2 chains of 2)
    if (w == (t & 3)) {
      f32x4 aL = {0.f, 0.f, 0.f, 0.f};
      aL = mfma16(ah0, wl_h[0], aL);
      aL = mfma16(ah1, wl_h[1], aL);
      f32x4 bL = {0.f, 0.f, 0.f, 0.f};
      bL = mfma16(ah0, wl_l[0], bL);
      bL = mfma16(ah1, wl_l[1], bL);
      aL = aL + bL;
      if (low == 0) *(f32x4*)&logitsT[t][q * 4] = aL;
    }

    // per-lane LSTM cell update (rows q*4+r, col 16w+low)
    short* hw = &hpl[t & 1][0][0];
#pragma unroll
    for (int r = 0; r < 4; ++r) {
      float gi = rcp_f(1.0f + EXP2(-acc[0][r]));
      float gf = rcp_f(1.0f + EXP2(-acc[1][r]));
      float gg = 1.0f - 2.0f * rcp_f(1.0f + EXP2(acc[2][r]));
      float go = rcp_f(1.0f + EXP2(-acc[3][r]));
      float cc = fmaf(gf, c4[r], gi * gg);
      c4[r] = cc;
      float h = go * (1.0f - 2.0f * rcp_f(1.0f + EXP2(cc * (2.0f * L2E))));
      hw[(q * 4 + r) * 72 + 16 * w + low] = bf16_rne(h);
    }

    if (tt == 4 && t + 4 < NSEQ) stage_write(cb ^ 1);
    __syncthreads();
  }

  // final logit from h_511 (in hpl[1])
  if (w == 0) {
    const short* hp = &hpl[1][low][0];
    s16x8 ah0 = *(const s16x8*)(hp + q * 8);
    s16x8 ah1 = *(const s16x8*)(hp + 32 + q * 8);
    f32x4 aL = {0.f, 0.f, 0.f, 0.f};
    aL = mfma16(ah0, wl_h[0], aL);
    aL = mfma16(ah1, wl_h[1], aL);
    f32x4 bL = {0.f, 0.f, 0.f, 0.f};
    bL = mfma16(ah0, wl_l[0], bL);
    bL = mfma16(ah1, wl_l[1], bL);
    aL = aL + bL;
    if (low == 0) *(f32x4*)&logitsT[NSEQ][q * 4] = aL;
  }
  __syncthreads();

  // ---- softmax over time: row m = u>>4, lanes cover t = (u&15) + 16s ----
  {
    const int m = u >> 4, li = u & 15;
    float lv[32];
    float mx = -3.0e38f;
#pragma unroll
    for (int s = 0; s < 32; ++s) {
      lv[s] = logitsT[1 + li + 16 * s][m];
      mx = fmaxf(mx, lv[s]);
    }
#pragma unroll
    for (int d = 1; d < 16; d <<= 1) mx = fmaxf(mx, __shfl_xor(mx, d, 16));
    float sum = 0.f;
#pragma unroll
    for (int s = 0; s < 32; ++s) { lv[s] = __expf(lv[s] - mx); sum += lv[s]; }
#pragma unroll
    for (int d = 1; d < 16; d <<= 1) sum += __shfl_xor(sum, d, 16);
    float inv = 1.0f / sum;
#pragma unroll
    for (int s = 0; s < 32; ++s)
      out[(size_t)(b0 + m) * NSEQ + li + 16 * s] = lv[s] * inv;
  }
}

// ---------------------------------------------------------------------------
extern "C" void kernel_launch(void* const* d_in, const int* in_sizes, int n_in,
                              void* d_out, int out_size, void* d_ws, size_t ws_size,
                              hipStream_t stream) {
  const float* x      = (const float*)d_in[0];
  const float* W_fc   = (const float*)d_in[1];
  const float* b_fc   = (const float*)d_in[2];
  const float* W_ih   = (const float*)d_in[3];
  const float* W_hh   = (const float*)d_in[4];
  const float* b_ih   = (const float*)d_in[5];
  const float* b_hh   = (const float*)d_in[6];
  const float* W_last = (const float*)d_in[7];
  // d_in[8] = b_last: cancels in softmax.

  float* out = (float*)d_out;
  float* wsW = (float*)d_ws;          // 256*32 floats
  float* wsB = wsW + 256 * 32;        // 256 floats

  prep_kernel<<<1, 256, 0, stream>>>(W_fc, b_fc, W_ih, b_ih, b_hh, wsW, wsB);
  lstm_mfma<<<B_SZ / MB, 256, 0, stream>>>(x, W_hh, wsW, wsB, W_last, out);
}

// Round 8
// 430.820 us; speedup vs baseline: 1.5234x; 1.0199x over previous
//
#include <hip/hip_runtime.h>

#define B_SZ  1024
#define NSEQ  512
#define D_INP 30
#define H     64
#define MB    16
#define TCH   8
#define L2E   1.4426950408889634f

typedef short s16x8 __attribute__((ext_vector_type(8)));
typedef float f32x4 __attribute__((ext_vector_type(4)));

#if __has_builtin(__builtin_amdgcn_exp2f)
#define EXP2(x) __builtin_amdgcn_exp2f(x)
#else
#define EXP2(x) exp2f(x)
#endif

__device__ __forceinline__ float rcp_f(float v) { return __builtin_amdgcn_rcpf(v); }

__device__ __forceinline__ f32x4 mfma16(s16x8 a, s16x8 b, f32x4 c) {
  return __builtin_amdgcn_mfma_f32_16x16x32_bf16(a, b, c, 0, 0, 0);
}

__device__ __forceinline__ short bf16_rne(float f) {
  unsigned u = __float_as_uint(f);
  unsigned r = (u + 0x7FFFu + ((u >> 16) & 1u)) >> 16;
  return (short)r;
}

__device__ __forceinline__ s16x8 rne8(const float* f) {
  s16x8 o;
#pragma unroll
  for (int i = 0; i < 8; ++i) o[i] = bf16_rne(f[i]);
  return o;
}

__device__ __forceinline__ void split8(const float* f, s16x8& hi, s16x8& lo) {
#pragma unroll
  for (int i = 0; i < 8; ++i) {
    unsigned ub = __float_as_uint(f[i]);
    hi[i] = (short)(ub >> 16);
    float hf = __uint_as_float(ub & 0xFFFF0000u);
    float lf = f[i] - hf;
    lo[i] = (short)(__float_as_uint(lf) >> 16);
  }
}

// ---------------------------------------------------------------------------
// Kernel A: fold FC into the input-side gate GEMM (fp32).
// ---------------------------------------------------------------------------
__global__ __launch_bounds__(256) void prep_kernel(
    const float* __restrict__ W_fc, const float* __restrict__ b_fc,
    const float* __restrict__ W_ih, const float* __restrict__ b_ih,
    const float* __restrict__ b_hh,
    float* __restrict__ wsW, float* __restrict__ wsB) {
  __shared__ float fc[H * D_INP];
  __shared__ float bfc[H];
  const int u = threadIdx.x;
  for (int i = u; i < H * D_INP; i += 256) fc[i] = W_fc[i];
  if (u < H) bfc[u] = b_fc[u];
  __syncthreads();

  float wih[H];
#pragma unroll
  for (int i = 0; i < H; ++i) wih[i] = W_ih[u * H + i];

  for (int k = 0; k < D_INP; ++k) {
    float s = 0.f;
#pragma unroll
    for (int i = 0; i < H; ++i) s = fmaf(wih[i], fc[i * D_INP + k], s);
    wsW[u * 32 + k] = s;
  }
  wsW[u * 32 + 30] = 0.f;
  wsW[u * 32 + 31] = 0.f;

  float bb = b_ih[u] + b_hh[u];
#pragma unroll
  for (int i = 0; i < H; ++i) bb = fmaf(wih[i], bfc[i], bb);
  wsB[u] = bb;
}

// ---------------------------------------------------------------------------
// Kernel B: MFMA LSTM, 64 blocks x 512 threads (8 waves, 2/SIMD).
// Wave w owns N-tiles {w, w+8}. Pair (c, c+4) shares SIMD c and col-block
// j in [16c,16c+16): wave c has gates {i,g}, wave c+4 has {f,o} + c-state.
// IG ships p = sig(i)*tanh(g) via lane-aligned b128 LDS exchange.
// Numerics identical to round 7 (single-plane RNE bf16, log2e prescale).
// ---------------------------------------------------------------------------
__global__ __launch_bounds__(512, 2) void lstm_mfma(
    const float* __restrict__ x, const float* __restrict__ W_hh,
    const float* __restrict__ wsW, const float* __restrict__ wsB,
    const float* __restrict__ W_last, float* __restrict__ out) {

  __shared__ short xa[2][TCH][64][8];              // 16 KB
  __shared__ short hpl[2][MB][72];                 // 4.6 KB
  __shared__ __align__(16) float exch[4][64][4];   // 4 KB
  __shared__ float logitsT[NSEQ + 1][MB];          // 32.8 KB

  const int u   = threadIdx.x;    // 0..511
  const int w   = u >> 6;         // wave 0..7
  const int l   = u & 63;
  const int low = l & 15;
  const int q   = l >> 4;
  const int b0  = blockIdx.x * MB;
  const bool isFO = (w >= 4);
  const int c = w & 3;            // pair / col-block id

  // ---- B-frags: tiles T0 = w (n0), T1 = w+8 (n1) ----
  const int n0 = 16 * w + low;          // gate i (IG) / f (FO)
  const int n1 = n0 + 128;              // gate g (IG) / o (FO)
  const float sc0 = L2E;
  const float sc1 = isFO ? L2E : (2.0f * L2E);

  s16x8 whh[2][2], wcb[2], wl_h[2], wl_l[2];
  float biasv0, biasv1;
  {
    float tmp[8];
#pragma unroll
    for (int kt = 0; kt < 2; ++kt) {
      const float* p = W_hh + n0 * H + kt * 32 + q * 8;
#pragma unroll
      for (int j = 0; j < 8; ++j) tmp[j] = p[j] * sc0;
      whh[0][kt] = rne8(tmp);
      const float* p1 = W_hh + n1 * H + kt * 32 + q * 8;
#pragma unroll
      for (int j = 0; j < 8; ++j) tmp[j] = p1[j] * sc1;
      whh[1][kt] = rne8(tmp);
    }
    const float* p = wsW + n0 * 32 + q * 8;
#pragma unroll
    for (int j = 0; j < 8; ++j) tmp[j] = p[j] * sc0;
    wcb[0] = rne8(tmp);
    const float* p1 = wsW + n1 * 32 + q * 8;
#pragma unroll
    for (int j = 0; j < 8; ++j) tmp[j] = p1[j] * sc1;
    wcb[1] = rne8(tmp);
    biasv0 = wsB[n0] * sc0;
    biasv1 = wsB[n1] * sc1;
  }
#pragma unroll
  for (int kt = 0; kt < 2; ++kt) {
    float tmp[8];
#pragma unroll
    for (int j = 0; j < 8; ++j)
      tmp[j] = (low == 0) ? W_last[kt * 32 + q * 8 + j] : 0.0f;
    split8(tmp, wl_h[kt], wl_l[kt]);
  }

  // zero h planes
  for (int i = u; i < 2 * MB * 72 / 2; i += 512) ((int*)hpl)[i] = 0;

  // ---- x staging: thread u -> chunk-slot ss, dest lane dl ----
  const int ss = u >> 6, dl = u & 63;
  const int srow = dl & 15, sq = dl >> 4;
  const float* xrow = x + (size_t)(b0 + srow) * NSEQ * D_INP + sq * 8;
  float pf[8];
  auto stage_load = [&](int t0) {
    const float* p = xrow + (size_t)(t0 + ss) * D_INP;
    float2 v0 = *(const float2*)(p);
    float2 v1 = *(const float2*)(p + 2);
    float2 v2 = *(const float2*)(p + 4);
    float2 v3 = (sq < 3) ? *(const float2*)(p + 6) : make_float2(0.f, 0.f);
    pf[0] = v0.x; pf[1] = v0.y; pf[2] = v1.x; pf[3] = v1.y;
    pf[4] = v2.x; pf[5] = v2.y; pf[6] = v3.x; pf[7] = v3.y;
  };
  auto stage_write = [&](int buf) {
    *(s16x8*)&xa[buf][ss][dl][0] = rne8(pf);
  };

  stage_load(0);
  stage_write(0);
  __syncthreads();

  f32x4 c4 = {0.f, 0.f, 0.f, 0.f};   // FO waves: cell state

  for (int t = 0; t < NSEQ; ++t) {
    const int tt = t & (TCH - 1);
    const int cb = (t >> 3) & 1;
    if (tt == 0 && t + TCH < NSEQ) stage_load(t + TCH);

    // ---- phase 1: A-frags + 6 MFMAs (all waves) ----
    s16x8 xah = *(const s16x8*)&xa[cb][tt][l][0];
    const short* hp = &hpl[(t + 1) & 1][low][0];
    s16x8 ah0 = *(const s16x8*)(hp + q * 8);
    s16x8 ah1 = *(const s16x8*)(hp + 32 + q * 8);

    f32x4 acc0 = {biasv0, biasv0, biasv0, biasv0};
    acc0 = mfma16(xah, wcb[0], acc0);
    acc0 = mfma16(ah0, whh[0][0], acc0);
    acc0 = mfma16(ah1, whh[0][1], acc0);
    f32x4 acc1 = {biasv1, biasv1, biasv1, biasv1};
    acc1 = mfma16(xah, wcb[1], acc1);
    acc1 = mfma16(ah0, whh[1][0], acc1);
    acc1 = mfma16(ah1, whh[1][1], acc1);

    // logit of h_{t-1}: rotating extra N-tile
    if (w == (t & 7)) {
      f32x4 aL = {0.f, 0.f, 0.f, 0.f};
      aL = mfma16(ah0, wl_h[0], aL);
      aL = mfma16(ah1, wl_h[1], aL);
      f32x4 bL = {0.f, 0.f, 0.f, 0.f};
      bL = mfma16(ah0, wl_l[0], bL);
      bL = mfma16(ah1, wl_l[1], bL);
      aL = aL + bL;
      if (low == 0) *(f32x4*)&logitsT[t][q * 4] = aL;
    }

    float gfv[4], gov[4];
    if (!isFO) {
      // IG: p = sig(i) * tanh(g), ship lane-aligned
      f32x4 p;
#pragma unroll
      for (int r = 0; r < 4; ++r) {
        float gi = rcp_f(1.0f + EXP2(-acc0[r]));
        float gg = 1.0f - 2.0f * rcp_f(1.0f + EXP2(acc1[r]));
        p[r] = gi * gg;
      }
      *(f32x4*)&exch[c][l][0] = p;
    } else {
      // FO: activate f, o while IG ships p
#pragma unroll
      for (int r = 0; r < 4; ++r) {
        gfv[r] = rcp_f(1.0f + EXP2(-acc0[r]));
        gov[r] = rcp_f(1.0f + EXP2(-acc1[r]));
      }
    }
    __syncthreads();

    // ---- phase 2: FO completes cells, writes h ----
    if (isFO) {
      f32x4 p = *(const f32x4*)&exch[c][l][0];
      const int j = 16 * c + low;
      short* hw = &hpl[t & 1][0][0];
#pragma unroll
      for (int r = 0; r < 4; ++r) {
        float cc = fmaf(gfv[r], c4[r], p[r]);
        c4[r] = cc;
        float h = gov[r] * (1.0f - 2.0f * rcp_f(1.0f + EXP2(cc * (2.0f * L2E))));
        hw[(q * 4 + r) * 72 + j] = bf16_rne(h);
      }
    }
    if (tt == 4 && t + 4 < NSEQ) stage_write(cb ^ 1);
    __syncthreads();
  }

  // final logit from h_511 (in hpl[1])
  if (w == 0) {
    const short* hp = &hpl[1][low][0];
    s16x8 ah0 = *(const s16x8*)(hp + q * 8);
    s16x8 ah1 = *(const s16x8*)(hp + 32 + q * 8);
    f32x4 aL = {0.f, 0.f, 0.f, 0.f};
    aL = mfma16(ah0, wl_h[0], aL);
    aL = mfma16(ah1, wl_h[1], aL);
    f32x4 bL = {0.f, 0.f, 0.f, 0.f};
    bL = mfma16(ah0, wl_l[0], bL);
    bL = mfma16(ah1, wl_l[1], bL);
    aL = aL + bL;
    if (low == 0) *(f32x4*)&logitsT[NSEQ][q * 4] = aL;
  }
  __syncthreads();

  // ---- softmax over time (first 256 threads) ----
  if (u < 256) {
    const int m = u >> 4, li = u & 15;
    float lv[32];
    float mx = -3.0e38f;
#pragma unroll
    for (int s = 0; s < 32; ++s) {
      lv[s] = logitsT[1 + li + 16 * s][m];
      mx = fmaxf(mx, lv[s]);
    }
#pragma unroll
    for (int d = 1; d < 16; d <<= 1) mx = fmaxf(mx, __shfl_xor(mx, d, 16));
    float sum = 0.f;
#pragma unroll
    for (int s = 0; s < 32; ++s) { lv[s] = __expf(lv[s] - mx); sum += lv[s]; }
#pragma unroll
    for (int d = 1; d < 16; d <<= 1) sum += __shfl_xor(sum, d, 16);
    float inv = 1.0f / sum;
#pragma unroll
    for (int s = 0; s < 32; ++s)
      out[(size_t)(b0 + m) * NSEQ + li + 16 * s] = lv[s] * inv;
  }
}

// ---------------------------------------------------------------------------
extern "C" void kernel_launch(void* const* d_in, const int* in_sizes, int n_in,
                              void* d_out, int out_size, void* d_ws, size_t ws_size,
                              hipStream_t stream) {
  const float* x      = (const float*)d_in[0];
  const float* W_fc   = (const float*)d_in[1];
  const float* b_fc   = (const float*)d_in[2];
  const float* W_ih   = (const float*)d_in[3];
  const float* W_hh   = (const float*)d_in[4];
  const float* b_ih   = (const float*)d_in[5];
  const float* b_hh   = (const float*)d_in[6];
  const float* W_last = (const float*)d_in[7];
  // d_in[8] = b_last: cancels in softmax.

  float* out = (float*)d_out;
  float* wsW = (float*)d_ws;          // 256*32 floats
  float* wsB = wsW + 256 * 32;        // 256 floats

  prep_kernel<<<1, 256, 0, stream>>>(W_fc, b_fc, W_ih, b_ih, b_hh, wsW, wsB);
  lstm_mfma<<<B_SZ / MB, 512, 0, stream>>>(x, W_hh, wsW, wsB, W_last, out);
}